// Round 5
// baseline (632.818 us; speedup 1.0000x reference)
//
#include <hip/hip_runtime.h>
#include <hip/hip_bf16.h>

#define NN 4096
#define FF 32
#define EE 65536
#define GG 13

typedef float floatx4 __attribute__((ext_vector_type(4)));
typedef __bf16 bf16x8 __attribute__((ext_vector_type(8)));
typedef short short8 __attribute__((ext_vector_type(8)));

__device__ inline unsigned short f2bf(float f) {
    unsigned u = __float_as_uint(f);
    u += 0x7FFFu + ((u >> 16) & 1u);          // RNE to bf16
    return (unsigned short)(u >> 16);
}

// ---------------- B-fragment prep kernels ----------------
// Bfrag layout: element (ks, t, c, kl) at ((ks*NTOT + t)*512 + c*32 + kl), bf16.
// ks = k/32 (K-step), t = col/16 (n-tile), c = col&15, kl = k&31.
// Lane l reads 8 contiguous bf16 at c=l&15, kl=(l>>4)*8 -> per-instr 1KB contiguous.

__global__ void k_prep1(const float* __restrict__ x, unsigned short* __restrict__ B) {
    int tid = blockIdx.x * 256 + threadIdx.x;           // < 4096*32
    int k = tid >> 5, col = tid & 31;
    float v = fabsf(x[tid]);
    B[(((k >> 5) * 2 + (col >> 4)) << 9) + ((col & 15) << 5) + (k & 31)] = f2bf(v);
}

__global__ void k_prep2(const float* __restrict__ P1, unsigned short* __restrict__ B) {
    int tid = blockIdx.x * 256 + threadIdx.x;           // < 4096*96
    int k = tid / 96, jf = tid % 96;
    int j = jf >> 5, f = jf & 31;
    float v = fabsf(P1[((1 + j) * NN + k) * FF + f]);   // |y1[j][k][f]|
    B[(((k >> 5) * 6 + (jf >> 4)) << 9) + ((jf & 15) << 5) + (k & 31)] = f2bf(v);
}

__global__ void k_prep3(const float* __restrict__ P2, unsigned short* __restrict__ B) {
    int tid = blockIdx.x * 256 + threadIdx.x;           // < 4096*288
    int k = tid / 288, cc = tid % 288;
    int k3 = cc / 96, jf = cc % 96;
    float v = fabsf(P2[((1 + k3) * NN + k) * 96 + jf]); // |y2[j][k3][k][f]|, col = k3*96+j*32+f
    B[(((k >> 5) * 18 + (cc >> 4)) << 9) + ((cc & 15) << 5) + (k & 31)] = f2bf(v);
}

// ---------------- Pass 1: register-streaming, 4-K-step load groups, fenced ------
// r0-r3 post-mortem: all four schedule variants = depth-1 per wave (~4 KB/wave in
// flight per ~1100-cy latency chain) -> 32 waves/CU x 4KB/1100cy = 3.7 B/cy/CU =
// the observed 2.3 TB/s. Limiter is bytes-in-flight per wave. This version: each
// wave's 16 K-steps go in 4 groups of 4; ALL 16 loads of a group (8KB A + 8KB B
// per wave) issue into named regs, then sched_barrier(0) pins them above the
// convert/store/MFMA cluster (hipcc cannot sink loads across the fence - the
// collapse that hit r2's rotation, VGPR=36). ~20KB per chain -> ~4x demand ->
// HBM/L3-bound. K-step order per accumulator identical to r2/r4 (ksg = wave+8i,
// ascending) -> identical numerics.
// Apack layout: [mat][tile(256)][ks(128)][c15*32 + q*8 + j] shorts, mat stride 1<<24.
__global__ __launch_bounds__(512, 4) void k_pass1(const float* __restrict__ Umat,
                                                  const float* __restrict__ Psi,
                                                  const unsigned short* __restrict__ Bfrag,
                                                  float* __restrict__ Pout,
                                                  unsigned short* __restrict__ Apack) {
    __shared__ float cs[2][16 * 32];
    int tile = blockIdx.x, mat = blockIdx.y;
    const float* A = (mat == 0) ? Umat : (Psi + (size_t)(mat - 1) * NN * NN);
    int tid = threadIdx.x;
    int wave = tid >> 6, lane = tid & 63;
    int c15 = lane & 15, q = lane >> 4;

    const float* ga = A + ((size_t)tile * 16 + c15) * NN + q * 8;   // + ksg*32 floats
    const unsigned short* bbase = Bfrag + (c15 << 5) + (q << 3);
    unsigned short* apk = Apack + ((size_t)mat << 24) + (size_t)tile * 65536
                          + (c15 << 5) + (q << 3);

    floatx4 acc0 = {0.f, 0.f, 0.f, 0.f}, acc1 = {0.f, 0.f, 0.f, 0.f};

#pragma unroll
    for (int grp = 0; grp < 4; grp++) {
        floatx4 fa0[4], fa1[4];
        short8 fb0[4], fb1[4];
        // ---- load cluster: 16 VMEM ops, 20 KB/wave, all in flight together ----
#pragma unroll
        for (int j = 0; j < 4; j++) {
            int ksg = wave + (grp * 4 + j) * 8;
            fa0[j] = *(const floatx4*)(ga + ksg * 32);
            fa1[j] = *(const floatx4*)(ga + ksg * 32 + 4);
            fb0[j] = *(const short8*)(bbase + (size_t)(ksg * 2 + 0) * 512);
            fb1[j] = *(const short8*)(bbase + (size_t)(ksg * 2 + 1) * 512);
        }
        __builtin_amdgcn_sched_barrier(0);     // loads may not sink below
        // ---- compute cluster: cvt + Apack store + 2 MFMA per K-step ----
#pragma unroll
        for (int j = 0; j < 4; j++) {
            int ksg = wave + (grp * 4 + j) * 8;
            short8 av;
            av[0]=f2bf(fa0[j][0]); av[1]=f2bf(fa0[j][1]);
            av[2]=f2bf(fa0[j][2]); av[3]=f2bf(fa0[j][3]);
            av[4]=f2bf(fa1[j][0]); av[5]=f2bf(fa1[j][1]);
            av[6]=f2bf(fa1[j][2]); av[7]=f2bf(fa1[j][3]);
            *(short8*)(apk + (size_t)ksg * 512) = av;
            bf16x8 ab = __builtin_bit_cast(bf16x8, av);
            acc0 = __builtin_amdgcn_mfma_f32_16x16x32_bf16(ab, __builtin_bit_cast(bf16x8, fb0[j]), acc0, 0, 0, 0);
            acc1 = __builtin_amdgcn_mfma_f32_16x16x32_bf16(ab, __builtin_bit_cast(bf16x8, fb1[j]), acc1, 0, 0, 0);
        }
        __builtin_amdgcn_sched_barrier(0);     // compute may not hoist above
    }

    // reduce partial K-sums across 8 waves: two LDS regions, 4 serialization steps
    int half = wave & 1;
    floatx4 acc[2] = {acc0, acc1};
    for (int w2 = 0; w2 < 4; w2++) {
        if ((wave >> 1) == w2) {
#pragma unroll
            for (int t = 0; t < 2; t++)
#pragma unroll
                for (int r = 0; r < 4; r++) {
                    int idx = (q * 4 + r) * 32 + t * 16 + c15;
                    if (w2 == 0) cs[half][idx] = acc[t][r];
                    else cs[half][idx] += acc[t][r];
                }
        }
        __syncthreads();
    }
    float* orow = Pout + ((size_t)mat * NN + (size_t)tile * 16) * 32;
    for (int i = tid; i < 16 * 32; i += 512) orow[i] = cs[0][i] + cs[1][i];
}

// ---------------- Passes 2/3: pre-packed bf16 streamer, M=32 row-pairs ----------
// Each block handles TWO 16-row tiles (2*tp, 2*tp+1). Every B fragment is loaded
// once and feeds 2 MFMAs -> B-side L2 traffic halved. Per-output accumulation
// order unchanged -> bit-identical numerics.
template <int NT, int NTOT>
__global__ __launch_bounds__(512) void k_passP(const unsigned short* __restrict__ Apack,
                                               const unsigned short* __restrict__ Bfrag,
                                               float* __restrict__ Pout) {
    constexpr int NC = NT * 16;
    constexpr int NCTOT = NTOT * 16;
    int tp = blockIdx.x;                      // tile pair: rows [2tp*16, 2tp*16+32)
    int mat = blockIdx.y;
    int cg = blockIdx.z;
    int tid = threadIdx.x;
    int wave = tid >> 6, lane = tid & 63;
    int c15 = lane & 15, q = lane >> 4;
    const unsigned short* ap0 = Apack + ((size_t)mat << 24) + (size_t)(2 * tp) * 65536
                                + (size_t)(wave * 16) * 512 + (c15 << 5) + (q << 3);
    const unsigned short* ap1 = ap0 + 65536;
    const unsigned short* bbase = Bfrag + (size_t)(wave * 16) * NTOT * 512
                                  + (size_t)(cg * NT) * 512 + (c15 << 5) + (q << 3);

    floatx4 acc0[NT], acc1[NT];
#pragma unroll
    for (int t = 0; t < NT; t++) {
        acc0[t] = (floatx4){0.f, 0.f, 0.f, 0.f};
        acc1[t] = (floatx4){0.f, 0.f, 0.f, 0.f};
    }

    for (int s = 0; s < 16; s++) {
        short8 a0 = *(const short8*)(ap0 + (size_t)s * 512);
        short8 a1 = *(const short8*)(ap1 + (size_t)s * 512);
        const unsigned short* bp = bbase + (size_t)s * NTOT * 512;
        bf16x8 ab0 = __builtin_bit_cast(bf16x8, a0);
        bf16x8 ab1 = __builtin_bit_cast(bf16x8, a1);
#pragma unroll
        for (int t = 0; t < NT; t++) {
            short8 bv = *(const short8*)(bp + t * 512);
            bf16x8 bb = __builtin_bit_cast(bf16x8, bv);
            acc0[t] = __builtin_amdgcn_mfma_f32_16x16x32_bf16(ab0, bb, acc0[t], 0, 0, 0);
            acc1[t] = __builtin_amdgcn_mfma_f32_16x16x32_bf16(ab1, bb, acc1[t], 0, 0, 0);
        }
    }

    __shared__ float cs[2][16 * NC];
    int half = wave & 1;

#define REDUCE_WRITE(ACC, TILE)                                                   \
    for (int w2 = 0; w2 < 4; w2++) {                                              \
        if ((wave >> 1) == w2) {                                                  \
            _Pragma("unroll")                                                     \
            for (int t = 0; t < NT; t++)                                          \
                _Pragma("unroll")                                                 \
                for (int r = 0; r < 4; r++) {                                     \
                    int idx = (q * 4 + r) * NC + t * 16 + c15;                    \
                    if (w2 == 0) cs[half][idx] = ACC[t][r];                       \
                    else cs[half][idx] += ACC[t][r];                              \
                }                                                                 \
        }                                                                         \
        __syncthreads();                                                          \
    }                                                                             \
    {                                                                             \
        float* orow = Pout + ((size_t)mat * NN + (size_t)(TILE) * 16) * NCTOT     \
                      + cg * NC;                                                  \
        for (int i = tid; i < 16 * NC; i += 512) {                                \
            int r = i / NC, c = i % NC;                                           \
            orow[(size_t)r * NCTOT + c] = cs[0][i] + cs[1][i];                    \
        }                                                                         \
    }

    REDUCE_WRITE(acc0, 2 * tp)
    __syncthreads();                          // cs reuse barrier between tiles
    REDUCE_WRITE(acc1, 2 * tp + 1)
#undef REDUCE_WRITE
}

// ---------------- GAT stage ----------------
// Fused h + attention logits: one wave per (g,n); lane = head*32+outfeat.
__global__ void k_hes(const float* __restrict__ P1, const float* __restrict__ P2,
                      const float* __restrict__ P3, const float* __restrict__ gatW,
                      const float* __restrict__ attS, const float* __restrict__ attD,
                      float* __restrict__ h, float* __restrict__ es,
                      float* __restrict__ ed) {
    int w = (blockIdx.x * 256 + threadIdx.x) >> 6;  // exactly 13*4096 waves
    int lane = threadIdx.x & 63;
    int g = w >> 12, n = w & 4095;
    const float* crow;
    if (g == 0) crow = P1 + (size_t)n * FF;
    else if (g <= 3) crow = P2 + (size_t)n * 96 + (g - 1) * 32;
    else {
        int j = (g - 4) / 3, k3 = (g - 4) % 3;
        crow = P3 + (size_t)n * 288 + k3 * 96 + j * 32;
    }
    const float* wcol = gatW + g * (32 * 64) + lane;
    float a = 0.f;
#pragma unroll
    for (int f = 0; f < 32; f++) a += crow[f] * wcol[f * 64];
    h[(size_t)w * 64 + lane] = a;
    float vs = a * attS[g * 64 + lane];
    float vd = a * attD[g * 64 + lane];
#pragma unroll
    for (int off = 16; off >= 1; off >>= 1) {
        vs += __shfl_down(vs, off, 32);
        vd += __shfl_down(vd, off, 32);
    }
    if ((lane & 31) == 0) {
        es[w * 2 + (lane >> 5)] = vs;
        ed[w * 2 + (lane >> 5)] = vd;
    }
}

// CSR build over dst (self-loops appended as nodes)
__global__ void k_hist(const int* __restrict__ ei, int* __restrict__ cnt) {
    int e = blockIdx.x * 256 + threadIdx.x;  // exactly EE+NN
    int d = (e < EE) ? ei[EE + e] : (e - EE);
    atomicAdd(&cnt[d], 1);
}

__global__ void k_scan(const int* __restrict__ cnt, int* __restrict__ offs,
                       int* __restrict__ cursor) {
    int lane = threadIdx.x;  // 64 threads, 1 block
    int base = lane * 64;
    int s = 0;
    for (int i = 0; i < 64; i++) s += cnt[base + i];
    int x = s;
    for (int d = 1; d < 64; d <<= 1) {
        int y = __shfl_up(x, d);
        if (lane >= d) x += y;
    }
    int run = x - s;  // exclusive prefix of per-lane totals
    for (int i = 0; i < 64; i++) {
        offs[base + i] = run;
        cursor[base + i] = run;
        run += cnt[base + i];
    }
}

__global__ void k_scatter(const int* __restrict__ ei, int* __restrict__ cursor,
                          int* __restrict__ csr) {
    int e = blockIdx.x * 256 + threadIdx.x;  // exactly EE+NN
    int s, d;
    if (e < EE) { s = ei[e]; d = ei[EE + e]; } else { s = d = e - EE; }
    int pos = atomicAdd(&cursor[d], 1);
    csr[pos] = s;
}

// One wave per (branch g, dst node n); lane = head*32 + feat. Online softmax,
// 2-deep software pipeline on the edge gather chain.
__global__ void k_gat(const float* __restrict__ h, const float* __restrict__ es,
                      const float* __restrict__ ed, const int* __restrict__ offs,
                      const int* __restrict__ cnt, const int* __restrict__ csr,
                      const float* __restrict__ gatb, float* __restrict__ gact) {
    int w = (blockIdx.x * 256 + threadIdx.x) >> 6;  // exactly 13*4096 waves
    int lane = threadIdx.x & 63, hh = lane >> 5;
    int g = w >> 12, n = w & 4095;
    float myed = ed[w * 2 + hh];
    float bias = gatb[g * 64 + lane];
    int start = offs[n], deg = cnt[n];   // deg >= 1 (self-loop)
    const float* hg = h + (size_t)g * NN * 64;
    const float* esg = es + (size_t)g * NN * 2;
    int sA = csr[start];
    int sB = (deg > 1) ? csr[start + 1] : 0;
    float hvA = hg[(size_t)sA * 64 + lane];
    float lgA = esg[sA * 2 + hh];
    float m = -INFINITY, z = 0.f, acc = 0.f;
    for (int i = 0; i < deg; i++) {
        int sC = (i + 2 < deg) ? csr[start + i + 2] : 0;
        float hvB = hg[(size_t)sB * 64 + lane];   // prefetch next (safe index)
        float lgB = esg[sB * 2 + hh];
        float lg = lgA + myed;
        lg = (lg > 0.f) ? lg : 0.2f * lg;               // leaky_relu(0.2)
        float nm = fmaxf(m, lg);
        float sc = __expf(m - nm);
        float we = __expf(lg - nm);
        z = z * sc + we;
        acc = acc * sc + we * hvA;
        m = nm;
        sA = sB; sB = sC; hvA = hvB; lgA = lgB;
    }
    float o = acc / (z + 1e-16f) + bias;
    o = (o > 0.f) ? o : (__expf(o) - 1.f);              // elu
    gact[(size_t)w * 64 + lane] = o;
}

// ---------------- Fused branch-MLP + head -------------------------------------
// One block per node: 13 waves, wave g computes feat[g][0..63] = elu(mlp) into
// LDS; wave 0 then does the head + log_softmax. Identical reduction orders to
// the split version -> bit-identical numerics.
__global__ __launch_bounds__(832) void k_out(const float* __restrict__ gact,
                                             const float* __restrict__ mlpW,
                                             const float* __restrict__ mlpb,
                                             const float* __restrict__ oW,
                                             const float* __restrict__ ob,
                                             float* __restrict__ out) {
    __shared__ float sf[832];
    int n = blockIdx.x;
    int g = threadIdx.x >> 6;        // 0..12
    int k = threadIdx.x & 63;
    const float* grow = gact + ((size_t)g * NN + n) * 64;
    const float* wc = mlpW + (size_t)g * 64 * 64 + k;
    float a = mlpb[g * 64 + k];
#pragma unroll 8
    for (int i = 0; i < 64; i++) a += grow[i] * wc[i * 64];
    a = (a > 0.f) ? a : (__expf(a) - 1.f);              // elu (pre-head)
    sf[g * 64 + k] = a;
    __syncthreads();
    if (g == 0) {
        float acc[10];
#pragma unroll
        for (int c = 0; c < 10; c++) acc[c] = 0.f;
#pragma unroll
        for (int i = 0; i < 13; i++) {
            float v = sf[i * 64 + k];
            const float* wp = oW + (i * 64 + k) * 10;
#pragma unroll
            for (int c = 0; c < 10; c++) acc[c] += v * wp[c];
        }
#pragma unroll
        for (int off = 32; off >= 1; off >>= 1)
#pragma unroll
            for (int c = 0; c < 10; c++) acc[c] += __shfl_down(acc[c], off);
        if (k == 0) {
            float m = -INFINITY;
#pragma unroll
            for (int c = 0; c < 10; c++) { acc[c] += ob[c]; m = fmaxf(m, acc[c]); }
            float s = 0.f;
#pragma unroll
            for (int c = 0; c < 10; c++) s += __expf(acc[c] - m);
            float lse = m + __logf(s);
#pragma unroll
            for (int c = 0; c < 10; c++) out[n * 10 + c] = acc[c] - lse;
        }
    }
}

extern "C" void kernel_launch(void* const* d_in, const int* in_sizes, int n_in,
                              void* d_out, int out_size, void* d_ws, size_t ws_size,
                              hipStream_t stream) {
    const float* x    = (const float*)d_in[0];
    const int*   ei   = (const int*)d_in[1];
    const float* U    = (const float*)d_in[2];
    const float* psi  = (const float*)d_in[3];
    const float* gatW = (const float*)d_in[4];
    const float* attS = (const float*)d_in[5];
    const float* attD = (const float*)d_in[6];
    const float* gatb = (const float*)d_in[7];
    const float* mlpW = (const float*)d_in[8];
    const float* mlpb = (const float*)d_in[9];
    const float* oW   = (const float*)d_in[10];
    const float* ob   = (const float*)d_in[11];
    float* out = (float*)d_out;

    char* ws = (char*)d_ws;
    size_t off = 0;
    auto alloc = [&](size_t bytes) { char* p = ws + off; off += (bytes + 255) & ~(size_t)255; return p; };
    unsigned short* Apack = (unsigned short*)alloc((size_t)4 * NN * NN * 2);  // 128 MB bf16 A-frags
    unsigned short* bf1 = (unsigned short*)alloc((size_t)NN * 32 * 2);
    float* P1           = (float*)alloc((size_t)4 * NN * 32 * 4);
    unsigned short* bf2 = (unsigned short*)alloc((size_t)NN * 96 * 2);
    float* P2           = (float*)alloc((size_t)4 * NN * 96 * 4);
    unsigned short* bf3 = (unsigned short*)alloc((size_t)NN * 288 * 2);
    float* P3           = (float*)alloc((size_t)NN * 288 * 4);
    float* h            = (float*)alloc((size_t)GG * NN * 64 * 4);
    float* es           = (float*)alloc((size_t)GG * NN * 2 * 4);
    float* ed           = (float*)alloc((size_t)GG * NN * 2 * 4);
    int* cnt            = (int*)alloc((size_t)NN * 4);
    int* offs           = (int*)alloc((size_t)NN * 4);
    int* cursor         = (int*)alloc((size_t)NN * 4);
    int* csr            = (int*)alloc((size_t)(EE + NN) * 4);
    float* gact         = (float*)alloc((size_t)GG * NN * 64 * 4);
    (void)ws_size; (void)in_sizes; (void)n_in; (void)out_size;

    // CSR build (independent of scattering passes)
    hipMemsetAsync(cnt, 0, NN * 4, stream);
    k_hist<<<(EE + NN) / 256, 256, 0, stream>>>(ei, cnt);
    k_scan<<<1, 64, 0, stream>>>(cnt, offs, cursor);
    k_scatter<<<(EE + NN) / 256, 256, 0, stream>>>(ei, cursor, csr);

    // Scattering passes
    k_prep1<<<(NN * 32) / 256, 256, 0, stream>>>(x, bf1);
    k_pass1<<<dim3(NN / 16, 4), 512, 0, stream>>>(U, psi, bf1, P1, Apack);
    k_prep2<<<(NN * 96) / 256, 256, 0, stream>>>(P1, bf2);
    k_passP<6, 6><<<dim3(NN / 32, 4, 1), 512, 0, stream>>>(Apack, bf2, P2);
    k_prep3<<<(NN * 288) / 256, 256, 0, stream>>>(P2, bf3);
    k_passP<6, 18><<<dim3(NN / 32, 1, 3), 512, 0, stream>>>(Apack, bf3, P3);

    // GAT stage
    k_hes<<<(GG * NN * 64) / 256, 256, 0, stream>>>(P1, P2, P3, gatW, attS, attD, h, es, ed);
    k_gat<<<(GG * NN * 64) / 256, 256, 0, stream>>>(h, es, ed, offs, cnt, csr, gatb, gact);
    k_out<<<NN, 832, 0, stream>>>(gact, mlpW, mlpb, oW, ob, out);
}

// Round 6
// 626.279 us; speedup vs baseline: 1.0104x; 1.0104x over previous
//
#include <hip/hip_runtime.h>
#include <hip/hip_bf16.h>

#define NN 4096
#define FF 32
#define EE 65536
#define GG 13

typedef float floatx4 __attribute__((ext_vector_type(4)));
typedef __bf16 bf16x8 __attribute__((ext_vector_type(8)));
typedef short short8 __attribute__((ext_vector_type(8)));

__device__ inline unsigned short f2bf(float f) {
    unsigned u = __float_as_uint(f);
    u += 0x7FFFu + ((u >> 16) & 1u);          // RNE to bf16
    return (unsigned short)(u >> 16);
}

// async global->LDS, 16B per lane; lds dest = wave-uniform base + lane*16
__device__ inline void gl2lds16(const float* g, float* l) {
    __builtin_amdgcn_global_load_lds(
        (__attribute__((address_space(1))) void*)(void*)(g),
        (__attribute__((address_space(3))) void*)(l), 16, 0, 0);
}

// ---------------- weight staging (r6) ----------------
// Theory: harness INPUT buffers read at ~2.3 TB/s (pass1: 268 MB / 117 us across
// five disjoint schedules) and may be poorly cached. k_hes/k_out logically
// re-read small input weight arrays thousands of times (mlpW ~870 MB, gatW
// ~436 MB of logical traffic). Stage all small weights into workspace once
// (~360 KB); all GAT-stage kernels read the copies. Bit-identical bytes.
#define W_GATW 0
#define W_ATTS 26624
#define W_ATTD 27456
#define W_GATB 28288
#define W_MLPW 29120
#define W_MLPB 82368
#define W_OW   83200
#define W_OB   91520
#define W_TOT  91530

__global__ void k_stagew(const float* __restrict__ gatW, const float* __restrict__ attS,
                         const float* __restrict__ attD, const float* __restrict__ gatb,
                         const float* __restrict__ mlpW, const float* __restrict__ mlpb,
                         const float* __restrict__ oW, const float* __restrict__ ob,
                         float* __restrict__ w) {
    int i = blockIdx.x * 256 + threadIdx.x;
    if (i < W_ATTS) w[i] = gatW[i];
    else if (i < W_ATTD) w[i] = attS[i - W_ATTS];
    else if (i < W_GATB) w[i] = attD[i - W_ATTD];
    else if (i < W_MLPW) w[i] = gatb[i - W_GATB];
    else if (i < W_MLPB) w[i] = mlpW[i - W_MLPW];
    else if (i < W_OW)   w[i] = mlpb[i - W_MLPB];
    else if (i < W_OB)   w[i] = oW[i - W_OW];
    else if (i < W_TOT)  w[i] = ob[i - W_OB];
}

// ---------------- B-fragment prep kernels ----------------
// Bfrag layout: element (ks, t, c, kl) at ((ks*NTOT + t)*512 + c*32 + kl), bf16.
// ks = k/32 (K-step), t = col/16 (n-tile), c = col&15, kl = k&31.
// Lane l reads 8 contiguous bf16 at c=l&15, kl=(l>>4)*8 -> per-instr 1KB contiguous.

__global__ void k_prep1(const float* __restrict__ x, unsigned short* __restrict__ B) {
    int tid = blockIdx.x * 256 + threadIdx.x;           // < 4096*32
    int k = tid >> 5, col = tid & 31;
    float v = fabsf(x[tid]);
    B[(((k >> 5) * 2 + (col >> 4)) << 9) + ((col & 15) << 5) + (k & 31)] = f2bf(v);
}

__global__ void k_prep2(const float* __restrict__ P1, unsigned short* __restrict__ B) {
    int tid = blockIdx.x * 256 + threadIdx.x;           // < 4096*96
    int k = tid / 96, jf = tid % 96;
    int j = jf >> 5, f = jf & 31;
    float v = fabsf(P1[((1 + j) * NN + k) * FF + f]);   // |y1[j][k][f]|
    B[(((k >> 5) * 6 + (jf >> 4)) << 9) + ((jf & 15) << 5) + (k & 31)] = f2bf(v);
}

__global__ void k_prep3(const float* __restrict__ P2, unsigned short* __restrict__ B) {
    int tid = blockIdx.x * 256 + threadIdx.x;           // < 4096*288
    int k = tid / 288, cc = tid % 288;
    int k3 = cc / 96, jf = cc % 96;
    float v = fabsf(P2[((1 + k3) * NN + k) * 96 + jf]); // |y2[j][k3][k][f]|, col = k3*96+j*32+f
    B[(((k >> 5) * 18 + (cc >> 4)) << 9) + ((cc & 15) << 5) + (k & 31)] = f2bf(v);
}

// ---------------- Pass 1: async-LDS staging, counted vmcnt + raw s_barrier ----
// r0-r5: FIVE structurally different schedules all measure 117-121 us. 268 MB
// input read / 117 us = 2.29 TB/s = the input-buffer read ceiling. Input-read-
// bound at floor; frozen permanently. (This is the best-of-five variant, r4.)
// Apack layout: [mat][tile(256)][ks(128)][c15*32 + q*8 + j] shorts, mat stride 1<<24.
__global__ __launch_bounds__(512, 8) void k_pass1(const float* __restrict__ Umat,
                                                  const float* __restrict__ Psi,
                                                  const unsigned short* __restrict__ Bfrag,
                                                  float* __restrict__ Pout,
                                                  unsigned short* __restrict__ Apack) {
    __shared__ float abuf[2][16 * 256];       // 2 x 16 KB, linear rows (no pad)
    __shared__ float cs[2][16 * 32];
    int tile = blockIdx.x, mat = blockIdx.y;
    const float* A = (mat == 0) ? Umat : (Psi + (size_t)(mat - 1) * NN * NN);
    int tid = threadIdx.x;
    int wave = tid >> 6, lane = tid & 63;
    int c15 = lane & 15, q = lane >> 4;

    const float* atile = A + (size_t)tile * 16 * NN;
    const unsigned short* bbase = Bfrag + (c15 << 5) + (q << 3);
    unsigned short* apk = Apack + ((size_t)mat << 24) + (size_t)tile * 65536
                          + (c15 << 5) + (q << 3);

    int r0 = 2 * wave, r1 = 2 * wave + 1;
    const float* g0 = atile + (size_t)r0 * NN + ((lane ^ (r0 & 7)) << 2);
    const float* g1 = atile + (size_t)r1 * NN + ((lane ^ (r1 & 7)) << 2);
    float* l0 = &abuf[0][wave * 512];
    float* l1 = &abuf[1][wave * 512];

    int swz = c15 & 7;
    int u0 = ((wave * 8 + q * 2 + 0) ^ swz) << 2;
    int u1 = ((wave * 8 + q * 2 + 1) ^ swz) << 2;
    int rowbase = c15 << 8;

    floatx4 acc0 = {0.f, 0.f, 0.f, 0.f}, acc1 = {0.f, 0.f, 0.f, 0.f};

    gl2lds16(g0, l0);
    gl2lds16(g1, l0 + 256);
    asm volatile("" ::: "memory");
    short8 pb0 = *(const short8*)(bbase + (size_t)(wave * 2 + 0) * 512);
    short8 pb1 = *(const short8*)(bbase + (size_t)(wave * 2 + 1) * 512);
    asm volatile("s_waitcnt vmcnt(2)" ::: "memory");
    __builtin_amdgcn_s_barrier();
    __builtin_amdgcn_sched_barrier(0);

    for (int c = 0; c < 16; c++) {
        const float* rb = abuf[c & 1];
        if (c < 15) {
            float* wbb = (c & 1) ? l0 : l1;
            gl2lds16(g0 + (size_t)(c + 1) * 256, wbb);
            gl2lds16(g1 + (size_t)(c + 1) * 256, wbb + 256);
        }
        asm volatile("" ::: "memory");
        int ksg = c * 8 + wave;
        floatx4 f0 = *(const floatx4*)(rb + rowbase + u0);
        floatx4 f1 = *(const floatx4*)(rb + rowbase + u1);
        short8 bv0 = pb0, bv1 = pb1;
        if (c < 15) {
            pb0 = *(const short8*)(bbase + (size_t)((ksg + 8) * 2 + 0) * 512);
            pb1 = *(const short8*)(bbase + (size_t)((ksg + 8) * 2 + 1) * 512);
        }
        short8 av;
        av[0]=f2bf(f0[0]); av[1]=f2bf(f0[1]); av[2]=f2bf(f0[2]); av[3]=f2bf(f0[3]);
        av[4]=f2bf(f1[0]); av[5]=f2bf(f1[1]); av[6]=f2bf(f1[2]); av[7]=f2bf(f1[3]);
        *(short8*)(apk + (size_t)ksg * 512) = av;
        bf16x8 ab = __builtin_bit_cast(bf16x8, av);
        acc0 = __builtin_amdgcn_mfma_f32_16x16x32_bf16(ab, __builtin_bit_cast(bf16x8, bv0), acc0, 0, 0, 0);
        acc1 = __builtin_amdgcn_mfma_f32_16x16x32_bf16(ab, __builtin_bit_cast(bf16x8, bv1), acc1, 0, 0, 0);
        if (c < 15) {
            asm volatile("s_waitcnt vmcnt(3)" ::: "memory");
            __builtin_amdgcn_s_barrier();
            __builtin_amdgcn_sched_barrier(0);
        }
    }

    int half = wave & 1;
    floatx4 acc[2] = {acc0, acc1};
    for (int w2 = 0; w2 < 4; w2++) {
        if ((wave >> 1) == w2) {
#pragma unroll
            for (int t = 0; t < 2; t++)
#pragma unroll
                for (int r = 0; r < 4; r++) {
                    int idx = (q * 4 + r) * 32 + t * 16 + c15;
                    if (w2 == 0) cs[half][idx] = acc[t][r];
                    else cs[half][idx] += acc[t][r];
                }
        }
        __syncthreads();
    }
    float* orow = Pout + ((size_t)mat * NN + (size_t)tile * 16) * 32;
    for (int i = tid; i < 16 * 32; i += 512) orow[i] = cs[0][i] + cs[1][i];
}

// ---------------- Passes 2/3: pre-packed bf16 streamer, M=32 row-pairs ----------
// Each block handles TWO 16-row tiles (2*tp, 2*tp+1). Every B fragment is loaded
// once and feeds 2 MFMAs -> B-side L2 traffic halved. Per-output accumulation
// order unchanged -> bit-identical numerics.
template <int NT, int NTOT>
__global__ __launch_bounds__(512) void k_passP(const unsigned short* __restrict__ Apack,
                                               const unsigned short* __restrict__ Bfrag,
                                               float* __restrict__ Pout) {
    constexpr int NC = NT * 16;
    constexpr int NCTOT = NTOT * 16;
    int tp = blockIdx.x;                      // tile pair: rows [2tp*16, 2tp*16+32)
    int mat = blockIdx.y;
    int cg = blockIdx.z;
    int tid = threadIdx.x;
    int wave = tid >> 6, lane = tid & 63;
    int c15 = lane & 15, q = lane >> 4;
    const unsigned short* ap0 = Apack + ((size_t)mat << 24) + (size_t)(2 * tp) * 65536
                                + (size_t)(wave * 16) * 512 + (c15 << 5) + (q << 3);
    const unsigned short* ap1 = ap0 + 65536;
    const unsigned short* bbase = Bfrag + (size_t)(wave * 16) * NTOT * 512
                                  + (size_t)(cg * NT) * 512 + (c15 << 5) + (q << 3);

    floatx4 acc0[NT], acc1[NT];
#pragma unroll
    for (int t = 0; t < NT; t++) {
        acc0[t] = (floatx4){0.f, 0.f, 0.f, 0.f};
        acc1[t] = (floatx4){0.f, 0.f, 0.f, 0.f};
    }

    for (int s = 0; s < 16; s++) {
        short8 a0 = *(const short8*)(ap0 + (size_t)s * 512);
        short8 a1 = *(const short8*)(ap1 + (size_t)s * 512);
        const unsigned short* bp = bbase + (size_t)s * NTOT * 512;
        bf16x8 ab0 = __builtin_bit_cast(bf16x8, a0);
        bf16x8 ab1 = __builtin_bit_cast(bf16x8, a1);
#pragma unroll
        for (int t = 0; t < NT; t++) {
            short8 bv = *(const short8*)(bp + t * 512);
            bf16x8 bb = __builtin_bit_cast(bf16x8, bv);
            acc0[t] = __builtin_amdgcn_mfma_f32_16x16x32_bf16(ab0, bb, acc0[t], 0, 0, 0);
            acc1[t] = __builtin_amdgcn_mfma_f32_16x16x32_bf16(ab1, bb, acc1[t], 0, 0, 0);
        }
    }

    __shared__ float cs[2][16 * NC];
    int half = wave & 1;

#define REDUCE_WRITE(ACC, TILE)                                                   \
    for (int w2 = 0; w2 < 4; w2++) {                                              \
        if ((wave >> 1) == w2) {                                                  \
            _Pragma("unroll")                                                     \
            for (int t = 0; t < NT; t++)                                          \
                _Pragma("unroll")                                                 \
                for (int r = 0; r < 4; r++) {                                     \
                    int idx = (q * 4 + r) * NC + t * 16 + c15;                    \
                    if (w2 == 0) cs[half][idx] = ACC[t][r];                       \
                    else cs[half][idx] += ACC[t][r];                              \
                }                                                                 \
        }                                                                         \
        __syncthreads();                                                          \
    }                                                                             \
    {                                                                             \
        float* orow = Pout + ((size_t)mat * NN + (size_t)(TILE) * 16) * NCTOT     \
                      + cg * NC;                                                  \
        for (int i = tid; i < 16 * NC; i += 512) {                                \
            int r = i / NC, c = i % NC;                                           \
            orow[(size_t)r * NCTOT + c] = cs[0][i] + cs[1][i];                    \
        }                                                                         \
    }

    REDUCE_WRITE(acc0, 2 * tp)
    __syncthreads();                          // cs reuse barrier between tiles
    REDUCE_WRITE(acc1, 2 * tp + 1)
#undef REDUCE_WRITE
}

// ---------------- GAT stage (reads STAGED weights) ----------------
// Fused h + attention logits: one wave per (g,n); lane = head*32+outfeat.
__global__ void k_hes(const float* __restrict__ P1, const float* __restrict__ P2,
                      const float* __restrict__ P3, const float* __restrict__ gatW,
                      const float* __restrict__ attS, const float* __restrict__ attD,
                      float* __restrict__ h, float* __restrict__ es,
                      float* __restrict__ ed) {
    int w = (blockIdx.x * 256 + threadIdx.x) >> 6;  // exactly 13*4096 waves
    int lane = threadIdx.x & 63;
    int g = w >> 12, n = w & 4095;
    const float* crow;
    if (g == 0) crow = P1 + (size_t)n * FF;
    else if (g <= 3) crow = P2 + (size_t)n * 96 + (g - 1) * 32;
    else {
        int j = (g - 4) / 3, k3 = (g - 4) % 3;
        crow = P3 + (size_t)n * 288 + k3 * 96 + j * 32;
    }
    const float* wcol = gatW + g * (32 * 64) + lane;
    float a = 0.f;
#pragma unroll
    for (int f = 0; f < 32; f++) a += crow[f] * wcol[f * 64];
    h[(size_t)w * 64 + lane] = a;
    float vs = a * attS[g * 64 + lane];
    float vd = a * attD[g * 64 + lane];
#pragma unroll
    for (int off = 16; off >= 1; off >>= 1) {
        vs += __shfl_down(vs, off, 32);
        vd += __shfl_down(vd, off, 32);
    }
    if ((lane & 31) == 0) {
        es[w * 2 + (lane >> 5)] = vs;
        ed[w * 2 + (lane >> 5)] = vd;
    }
}

// CSR build over dst (self-loops appended as nodes)
__global__ void k_hist(const int* __restrict__ ei, int* __restrict__ cnt) {
    int e = blockIdx.x * 256 + threadIdx.x;  // exactly EE+NN
    int d = (e < EE) ? ei[EE + e] : (e - EE);
    atomicAdd(&cnt[d], 1);
}

__global__ void k_scan(const int* __restrict__ cnt, int* __restrict__ offs,
                       int* __restrict__ cursor) {
    int lane = threadIdx.x;  // 64 threads, 1 block
    int base = lane * 64;
    int s = 0;
    for (int i = 0; i < 64; i++) s += cnt[base + i];
    int x = s;
    for (int d = 1; d < 64; d <<= 1) {
        int y = __shfl_up(x, d);
        if (lane >= d) x += y;
    }
    int run = x - s;  // exclusive prefix of per-lane totals
    for (int i = 0; i < 64; i++) {
        offs[base + i] = run;
        cursor[base + i] = run;
        run += cnt[base + i];
    }
}

__global__ void k_scatter(const int* __restrict__ ei, int* __restrict__ cursor,
                          int* __restrict__ csr) {
    int e = blockIdx.x * 256 + threadIdx.x;  // exactly EE+NN
    int s, d;
    if (e < EE) { s = ei[e]; d = ei[EE + e]; } else { s = d = e - EE; }
    int pos = atomicAdd(&cursor[d], 1);
    csr[pos] = s;
}

// One wave per (branch g, dst node n); lane = head*32 + feat. Online softmax,
// 2-deep software pipeline on the edge gather chain.
__global__ void k_gat(const float* __restrict__ h, const float* __restrict__ es,
                      const float* __restrict__ ed, const int* __restrict__ offs,
                      const int* __restrict__ cnt, const int* __restrict__ csr,
                      const float* __restrict__ gatb, float* __restrict__ gact) {
    int w = (blockIdx.x * 256 + threadIdx.x) >> 6;  // exactly 13*4096 waves
    int lane = threadIdx.x & 63, hh = lane >> 5;
    int g = w >> 12, n = w & 4095;
    float myed = ed[w * 2 + hh];
    float bias = gatb[g * 64 + lane];
    int start = offs[n], deg = cnt[n];   // deg >= 1 (self-loop)
    const float* hg = h + (size_t)g * NN * 64;
    const float* esg = es + (size_t)g * NN * 2;
    int sA = csr[start];
    int sB = (deg > 1) ? csr[start + 1] : 0;
    float hvA = hg[(size_t)sA * 64 + lane];
    float lgA = esg[sA * 2 + hh];
    float m = -INFINITY, z = 0.f, acc = 0.f;
    for (int i = 0; i < deg; i++) {
        int sC = (i + 2 < deg) ? csr[start + i + 2] : 0;
        float hvB = hg[(size_t)sB * 64 + lane];   // prefetch next (safe index)
        float lgB = esg[sB * 2 + hh];
        float lg = lgA + myed;
        lg = (lg > 0.f) ? lg : 0.2f * lg;               // leaky_relu(0.2)
        float nm = fmaxf(m, lg);
        float sc = __expf(m - nm);
        float we = __expf(lg - nm);
        z = z * sc + we;
        acc = acc * sc + we * hvA;
        m = nm;
        sA = sB; sB = sC; hvA = hvB; lgA = lgB;
    }
    float o = acc / (z + 1e-16f) + bias;
    o = (o > 0.f) ? o : (__expf(o) - 1.f);              // elu
    gact[(size_t)w * 64 + lane] = o;
}

// ---------------- Fused branch-MLP + head (reads STAGED weights) ---------------
// One block per node: 13 waves, wave g computes feat[g][0..63] = elu(mlp) into
// LDS; wave 0 then does the head + log_softmax. Identical reduction orders to
// the split version -> bit-identical numerics.
__global__ __launch_bounds__(832) void k_out(const float* __restrict__ gact,
                                             const float* __restrict__ mlpW,
                                             const float* __restrict__ mlpb,
                                             const float* __restrict__ oW,
                                             const float* __restrict__ ob,
                                             float* __restrict__ out) {
    __shared__ float sf[832];
    int n = blockIdx.x;
    int g = threadIdx.x >> 6;        // 0..12
    int k = threadIdx.x & 63;
    const float* grow = gact + ((size_t)g * NN + n) * 64;
    const float* wc = mlpW + (size_t)g * 64 * 64 + k;
    float a = mlpb[g * 64 + k];
#pragma unroll 8
    for (int i = 0; i < 64; i++) a += grow[i] * wc[i * 64];
    a = (a > 0.f) ? a : (__expf(a) - 1.f);              // elu (pre-head)
    sf[g * 64 + k] = a;
    __syncthreads();
    if (g == 0) {
        float acc[10];
#pragma unroll
        for (int c = 0; c < 10; c++) acc[c] = 0.f;
#pragma unroll
        for (int i = 0; i < 13; i++) {
            float v = sf[i * 64 + k];
            const float* wp = oW + (i * 64 + k) * 10;
#pragma unroll
            for (int c = 0; c < 10; c++) acc[c] += v * wp[c];
        }
#pragma unroll
        for (int off = 32; off >= 1; off >>= 1)
#pragma unroll
            for (int c = 0; c < 10; c++) acc[c] += __shfl_down(acc[c], off);
        if (k == 0) {
            float m = -INFINITY;
#pragma unroll
            for (int c = 0; c < 10; c++) { acc[c] += ob[c]; m = fmaxf(m, acc[c]); }
            float s = 0.f;
#pragma unroll
            for (int c = 0; c < 10; c++) s += __expf(acc[c] - m);
            float lse = m + __logf(s);
#pragma unroll
            for (int c = 0; c < 10; c++) out[n * 10 + c] = acc[c] - lse;
        }
    }
}

extern "C" void kernel_launch(void* const* d_in, const int* in_sizes, int n_in,
                              void* d_out, int out_size, void* d_ws, size_t ws_size,
                              hipStream_t stream) {
    const float* x    = (const float*)d_in[0];
    const int*   ei   = (const int*)d_in[1];
    const float* U    = (const float*)d_in[2];
    const float* psi  = (const float*)d_in[3];
    const float* gatW = (const float*)d_in[4];
    const float* attS = (const float*)d_in[5];
    const float* attD = (const float*)d_in[6];
    const float* gatb = (const float*)d_in[7];
    const float* mlpW = (const float*)d_in[8];
    const float* mlpb = (const float*)d_in[9];
    const float* oW   = (const float*)d_in[10];
    const float* ob   = (const float*)d_in[11];
    float* out = (float*)d_out;

    char* ws = (char*)d_ws;
    size_t off = 0;
    auto alloc = [&](size_t bytes) { char* p = ws + off; off += (bytes + 255) & ~(size_t)255; return p; };
    unsigned short* Apack = (unsigned short*)alloc((size_t)4 * NN * NN * 2);  // 128 MB bf16 A-frags
    unsigned short* bf1 = (unsigned short*)alloc((size_t)NN * 32 * 2);
    float* P1           = (float*)alloc((size_t)4 * NN * 32 * 4);
    unsigned short* bf2 = (unsigned short*)alloc((size_t)NN * 96 * 2);
    float* P2           = (float*)alloc((size_t)4 * NN * 96 * 4);
    unsigned short* bf3 = (unsigned short*)alloc((size_t)NN * 288 * 2);
    float* P3           = (float*)alloc((size_t)NN * 288 * 4);
    float* h            = (float*)alloc((size_t)GG * NN * 64 * 4);
    float* es           = (float*)alloc((size_t)GG * NN * 2 * 4);
    float* ed           = (float*)alloc((size_t)GG * NN * 2 * 4);
    int* cnt            = (int*)alloc((size_t)NN * 4);
    int* offs           = (int*)alloc((size_t)NN * 4);
    int* cursor         = (int*)alloc((size_t)NN * 4);
    int* csr            = (int*)alloc((size_t)(EE + NN) * 4);
    float* gact         = (float*)alloc((size_t)GG * NN * 64 * 4);
    float* wst          = (float*)alloc((size_t)(W_TOT + 128) * 4);  // staged weights
    (void)ws_size; (void)in_sizes; (void)n_in; (void)out_size;

    const float* sgatW = wst + W_GATW;
    const float* sattS = wst + W_ATTS;
    const float* sattD = wst + W_ATTD;
    const float* sgatb = wst + W_GATB;
    const float* smlpW = wst + W_MLPW;
    const float* smlpb = wst + W_MLPB;
    const float* soW   = wst + W_OW;
    const float* sob   = wst + W_OB;

    // stage weights first (tiny)
    k_stagew<<<(W_TOT + 255) / 256, 256, 0, stream>>>(gatW, attS, attD, gatb,
                                                      mlpW, mlpb, oW, ob, wst);

    // CSR build (independent of scattering passes)
    hipMemsetAsync(cnt, 0, NN * 4, stream);
    k_hist<<<(EE + NN) / 256, 256, 0, stream>>>(ei, cnt);
    k_scan<<<1, 64, 0, stream>>>(cnt, offs, cursor);
    k_scatter<<<(EE + NN) / 256, 256, 0, stream>>>(ei, cursor, csr);

    // Scattering passes
    k_prep1<<<(NN * 32) / 256, 256, 0, stream>>>(x, bf1);
    k_pass1<<<dim3(NN / 16, 4), 512, 0, stream>>>(U, psi, bf1, P1, Apack);
    k_prep2<<<(NN * 96) / 256, 256, 0, stream>>>(P1, bf2);
    k_passP<6, 6><<<dim3(NN / 32, 4, 1), 512, 0, stream>>>(Apack, bf2, P2);
    k_prep3<<<(NN * 288) / 256, 256, 0, stream>>>(P2, bf3);
    k_passP<6, 18><<<dim3(NN / 32, 1, 3), 512, 0, stream>>>(Apack, bf3, P3);

    // GAT stage (staged weights)
    k_hes<<<(GG * NN * 64) / 256, 256, 0, stream>>>(P1, P2, P3, sgatW, sattS, sattD, h, es, ed);
    k_gat<<<(GG * NN * 64) / 256, 256, 0, stream>>>(h, es, ed, offs, cnt, csr, sgatb, gact);
    k_out<<<NN, 832, 0, stream>>>(gact, smlpW, smlpb, soW, sob, out);
}